// Round 1
// baseline (284.512 us; speedup 1.0000x reference)
//
#include <hip/hip_runtime.h>
#include <cstdint>
#include <cstddef>

typedef __attribute__((ext_vector_type(8))) short short8;     // 8 bf16 (4 VGPRs)
typedef __attribute__((ext_vector_type(4))) float f32x4;      // MFMA acc
typedef __attribute__((ext_vector_type(4))) unsigned short u16x4;
typedef __attribute__((ext_vector_type(4))) float float4v;

#define ASYNC16(gp, lp) \
  __builtin_amdgcn_global_load_lds((const __attribute__((address_space(1))) unsigned int*)(gp), \
                                   (__attribute__((address_space(3))) unsigned int*)(lp), 16, 0, 0)

__device__ __forceinline__ unsigned short f2b(float f) {
  union { float f; unsigned int u; } c; c.f = f;
  unsigned int u = c.u;
  return (unsigned short)((u + 0x7fffu + ((u >> 16) & 1u)) >> 16);
}

// ---------------- conversion kernels ----------------

__global__ void cvt_bf16(const float* __restrict__ X, unsigned short* __restrict__ Y, int n) {
  int i = (blockIdx.x * 256 + threadIdx.x) * 4;
  if (i < n) {
    const float* px = X + i;
    float a = px[0], b = px[1], c = px[2], d = px[3];
    u16x4 u;
    u[0] = f2b(a); u[1] = f2b(b); u[2] = f2b(c); u[3] = f2b(d);
    *(u16x4*)(Y + i) = u;
  }
}

// W [Kd][Nd] fp32 -> WT [Nd][Kd] bf16, 64x64 tiles
__global__ void transpose_cvt(const float* __restrict__ W, unsigned short* __restrict__ WT,
                              int Kd, int Nd) {
  __shared__ unsigned short Ts[64][65];
  int n0 = blockIdx.x * 64, k0 = blockIdx.y * 64;
  int tid = threadIdx.x;
  for (int idx = tid; idx < 4096; idx += 256) {
    int lr = idx >> 6, lc = idx & 63;
    Ts[lr][lc] = f2b(W[(size_t)(k0 + lr) * Nd + n0 + lc]);
  }
  __syncthreads();
  for (int idx = tid; idx < 4096; idx += 256) {
    int nr = idx >> 6, kc = idx & 63;
    WT[(size_t)(n0 + nr) * Kd + k0 + kc] = Ts[kc][nr];
  }
}

// ---------------- GEMM 1: qkv = x @ w_attn + b, scatter to q/k/vT ----------------

__global__ __launch_bounds__(256, 2) void gemm_qkv(
    const unsigned short* __restrict__ A,   // xb [8192][768]
    const unsigned short* __restrict__ Bt,  // waT [2304][768]
    const float* __restrict__ bias,         // [2304]
    unsigned short* __restrict__ q,         // [96][1024][64], pre-scaled by 0.125
    unsigned short* __restrict__ k,         // [96][1024][64]
    unsigned short* __restrict__ vT)        // [96][64][1024]
{
  __shared__ unsigned short As[128 * 32];
  __shared__ unsigned short Bs[128 * 32];
  const int tid = threadIdx.x;
  const int w = tid >> 6, lane = tid & 63;
  const int wm = w >> 1, wn = w & 1;
  const int lr = lane & 15, lq = lane >> 4;
  const int m0 = blockIdx.x * 128, n0 = blockIdx.y * 128;
  const f32x4 fzero = {0.f, 0.f, 0.f, 0.f};

  f32x4 acc[4][4];
  for (int i = 0; i < 4; ++i) for (int j = 0; j < 4; ++j) acc[i][j] = fzero;

  for (int kk0 = 0; kk0 < 768; kk0 += 32) {
    __syncthreads();
    for (int c = 0; c < 2; ++c) {
      int base = (c * 4 + w) * 1024;            // byte offset into 8 KB LDS tile
      int e = (base >> 1) + lane * 8;           // element index
      int row = e >> 5, kc = e & 31;
      ASYNC16(A  + (size_t)(m0 + row) * 768 + kk0 + kc, (char*)As + base);
      ASYNC16(Bt + (size_t)(n0 + row) * 768 + kk0 + kc, (char*)Bs + base);
    }
    __builtin_amdgcn_s_waitcnt(0);
    __syncthreads();

    short8 a[4], b[4];
    for (int i = 0; i < 4; ++i)
      a[i] = *(const short8*)(As + (wm * 64 + i * 16 + lr) * 32 + lq * 8);
    for (int j = 0; j < 4; ++j)
      b[j] = *(const short8*)(Bs + (wn * 64 + j * 16 + lr) * 32 + lq * 8);
    for (int i = 0; i < 4; ++i)
      for (int j = 0; j < 4; ++j)
        acc[i][j] = __builtin_amdgcn_mfma_f32_16x16x32_bf16(a[i], b[j], acc[i][j], 0, 0, 0);
  }

  // epilogue: each 128-col tile lies entirely in one of q/k/v (768 % 128 tiles align)
  const int colbase = n0 + wn * 64;
  const int sec = colbase / 768;                // 0=q, 1=k, 2=v (block-uniform)
  for (int j = 0; j < 4; ++j) {
    int col = colbase + j * 16 + lr;
    int cc = col - sec * 768;
    int h = cc >> 6, d = cc & 63;
    float bv = bias[col];
    for (int i = 0; i < 4; ++i) {
      int row0 = m0 + wm * 64 + i * 16 + lq * 4;
      int bidx = row0 >> 10, t0 = row0 & 1023;
      int bh = bidx * 12 + h;
      if (sec == 0) {
        for (int r = 0; r < 4; ++r)
          q[((size_t)bh * 1024 + t0 + r) * 64 + d] = f2b((acc[i][j][r] + bv) * 0.125f);
      } else if (sec == 1) {
        for (int r = 0; r < 4; ++r)
          k[((size_t)bh * 1024 + t0 + r) * 64 + d] = f2b(acc[i][j][r] + bv);
      } else {
        u16x4 pv;
        pv[0] = f2b(acc[i][j][0] + bv);
        pv[1] = f2b(acc[i][j][1] + bv);
        pv[2] = f2b(acc[i][j][2] + bv);
        pv[3] = f2b(acc[i][j][3] + bv);
        *(u16x4*)(vT + ((size_t)bh * 64 + d) * 1024 + t0) = pv;
      }
    }
  }
}

// ---------------- flash attention ----------------
// grid (8, 96): blockIdx.x = q-tile (128 rows), blockIdx.y = b*12+h

__global__ __launch_bounds__(256, 2) void attn(
    const unsigned short* __restrict__ q,
    const unsigned short* __restrict__ kk,
    const unsigned short* __restrict__ vT,
    unsigned short* __restrict__ y)         // [8192][768]
{
  __shared__ unsigned short Qs[128 * 72];   // stride 72: 2-way bank alias (free)
  __shared__ unsigned short Ks[64 * 72];
  __shared__ unsigned short Vt[64 * 72];    // [d][n]
  __shared__ unsigned short Ps[4 * 32 * 80];

  const int tid = threadIdx.x;
  const int w = tid >> 6, lane = tid & 63;
  const int lr = lane & 15, lq = lane >> 4;
  const int q0 = blockIdx.x * 128;
  const int bh = blockIdx.y;
  const int b = bh / 12, h = bh - b * 12;
  const f32x4 fzero = {0.f, 0.f, 0.f, 0.f};

  const unsigned short* qptr = q + ((size_t)bh * 1024 + q0) * 64;
  for (int c = tid; c < 1024; c += 256) {
    int row = c >> 3, d0 = (c & 7) * 8;
    *(short8*)(Qs + row * 72 + d0) = *(const short8*)(qptr + (size_t)c * 8);
  }

  float m_s[2][4], l_s[2][4], alpha[2][4];
  f32x4 o[2][4];
  for (int i = 0; i < 2; ++i)
    for (int r = 0; r < 4; ++r) { m_s[i][r] = -1e30f; l_s[i][r] = 0.0f; }
  for (int i = 0; i < 2; ++i)
    for (int jd = 0; jd < 4; ++jd) o[i][jd] = fzero;

  unsigned short* Pw = Ps + w * 32 * 80;
  const int nkt = q0 / 64 + 2;

  for (int kt = 0; kt < nkt; ++kt) {
    const int kt0 = kt * 64;
    __syncthreads();
    const unsigned short* kptr = kk + ((size_t)bh * 1024 + kt0) * 64;
    for (int c = tid; c < 512; c += 256) {
      int row = c >> 3, d0 = (c & 7) * 8;
      *(short8*)(Ks + row * 72 + d0) = *(const short8*)(kptr + (size_t)c * 8);
    }
    const unsigned short* vptr = vT + (size_t)bh * 64 * 1024 + kt0;
    for (int c = tid; c < 512; c += 256) {
      int d = c >> 3, nn = (c & 7) * 8;
      *(short8*)(Vt + d * 72 + nn) = *(const short8*)(vptr + (size_t)d * 1024 + nn);
    }
    __syncthreads();

    if (kt0 <= q0 + w * 32 + 31) {          // wave has at least one unmasked row
      f32x4 s[2][4];
      for (int i = 0; i < 2; ++i) for (int j = 0; j < 4; ++j) s[i][j] = fzero;
      for (int ks = 0; ks < 2; ++ks) {
        short8 aq[2], bk[4];
        for (int i = 0; i < 2; ++i)
          aq[i] = *(const short8*)(Qs + (w * 32 + i * 16 + lr) * 72 + ks * 32 + lq * 8);
        for (int j = 0; j < 4; ++j)
          bk[j] = *(const short8*)(Ks + (j * 16 + lr) * 72 + ks * 32 + lq * 8);
        for (int i = 0; i < 2; ++i)
          for (int j = 0; j < 4; ++j)
            s[i][j] = __builtin_amdgcn_mfma_f32_16x16x32_bf16(aq[i], bk[j], s[i][j], 0, 0, 0);
      }
      if (kt0 + 63 > q0 + w * 32) {         // causal mask needed
        for (int i = 0; i < 2; ++i) {
          int rowg = q0 + w * 32 + i * 16 + lq * 4;
          for (int j = 0; j < 4; ++j) {
            int colg = kt0 + j * 16 + lr;
            for (int r = 0; r < 4; ++r)
              if (colg > rowg + r) s[i][j][r] = -1e30f;
          }
        }
      }
      for (int i = 0; i < 2; ++i) {
        for (int r = 0; r < 4; ++r) {
          float mx = fmaxf(fmaxf(s[i][0][r], s[i][1][r]), fmaxf(s[i][2][r], s[i][3][r]));
          for (int off = 1; off < 16; off <<= 1)
            mx = fmaxf(mx, __shfl_xor(mx, off, 16));
          float mo = m_s[i][r];
          float mn = fmaxf(mo, mx);
          float al = __expf(mo - mn);
          float rs = 0.0f;
          int prow = (i * 16 + lq * 4 + r) * 80;
          for (int j = 0; j < 4; ++j) {
            float p = __expf(s[i][j][r] - mn);
            rs += p;
            Pw[prow + j * 16 + lr] = f2b(p);
          }
          for (int off = 1; off < 16; off <<= 1)
            rs += __shfl_xor(rs, off, 16);
          l_s[i][r] = l_s[i][r] * al + rs;
          m_s[i][r] = mn;
          alpha[i][r] = al;
        }
      }
      for (int i = 0; i < 2; ++i)
        for (int jd = 0; jd < 4; ++jd)
          for (int r = 0; r < 4; ++r)
            o[i][jd][r] *= alpha[i][r];
      __builtin_amdgcn_s_waitcnt(0);        // drain P writes before A-frag reads (same wave)
      for (int ks = 0; ks < 2; ++ks) {
        short8 ap[2], bv[4];
        for (int i = 0; i < 2; ++i)
          ap[i] = *(const short8*)(Pw + (i * 16 + lr) * 80 + ks * 32 + lq * 8);
        for (int jd = 0; jd < 4; ++jd)
          bv[jd] = *(const short8*)(Vt + (jd * 16 + lr) * 72 + ks * 32 + lq * 8);
        for (int i = 0; i < 2; ++i)
          for (int jd = 0; jd < 4; ++jd)
            o[i][jd] = __builtin_amdgcn_mfma_f32_16x16x32_bf16(ap[i], bv[jd], o[i][jd], 0, 0, 0);
      }
    }
  }

  for (int i = 0; i < 2; ++i) {
    int t = q0 + w * 32 + i * 16 + lq * 4;
    for (int jd = 0; jd < 4; ++jd) {
      int d = jd * 16 + lr;
      for (int r = 0; r < 4; ++r) {
        float ov = o[i][jd][r] / l_s[i][r];
        y[((size_t)b * 1024 + t + r) * 768 + h * 64 + d] = f2b(ov);
      }
    }
  }
}

// ---------------- GEMM 2: out = y @ w_proj + b ----------------

__global__ __launch_bounds__(256, 2) void gemm_proj(
    const unsigned short* __restrict__ A,   // y [8192][768]
    const unsigned short* __restrict__ Bt,  // wpT [768][768]
    const float* __restrict__ bias,         // [768]
    float* __restrict__ out)                // [8192][768] fp32
{
  __shared__ unsigned short As[128 * 32];
  __shared__ unsigned short Bs[128 * 32];
  const int tid = threadIdx.x;
  const int w = tid >> 6, lane = tid & 63;
  const int wm = w >> 1, wn = w & 1;
  const int lr = lane & 15, lq = lane >> 4;
  const int m0 = blockIdx.x * 128, n0 = blockIdx.y * 128;
  const f32x4 fzero = {0.f, 0.f, 0.f, 0.f};

  f32x4 acc[4][4];
  for (int i = 0; i < 4; ++i) for (int j = 0; j < 4; ++j) acc[i][j] = fzero;

  for (int kk0 = 0; kk0 < 768; kk0 += 32) {
    __syncthreads();
    for (int c = 0; c < 2; ++c) {
      int base = (c * 4 + w) * 1024;
      int e = (base >> 1) + lane * 8;
      int row = e >> 5, kc = e & 31;
      ASYNC16(A  + (size_t)(m0 + row) * 768 + kk0 + kc, (char*)As + base);
      ASYNC16(Bt + (size_t)(n0 + row) * 768 + kk0 + kc, (char*)Bs + base);
    }
    __builtin_amdgcn_s_waitcnt(0);
    __syncthreads();

    short8 a[4], b[4];
    for (int i = 0; i < 4; ++i)
      a[i] = *(const short8*)(As + (wm * 64 + i * 16 + lr) * 32 + lq * 8);
    for (int j = 0; j < 4; ++j)
      b[j] = *(const short8*)(Bs + (wn * 64 + j * 16 + lr) * 32 + lq * 8);
    for (int i = 0; i < 4; ++i)
      for (int j = 0; j < 4; ++j)
        acc[i][j] = __builtin_amdgcn_mfma_f32_16x16x32_bf16(a[i], b[j], acc[i][j], 0, 0, 0);
  }

  for (int j = 0; j < 4; ++j) {
    int col = n0 + wn * 64 + j * 16 + lr;
    float bv = bias[col];
    for (int i = 0; i < 4; ++i) {
      int row0 = m0 + wm * 64 + i * 16 + lq * 4;
      for (int r = 0; r < 4; ++r)
        out[(size_t)(row0 + r) * 768 + col] = acc[i][j][r] + bv;
    }
  }
}

// ---------------- launch ----------------

extern "C" void kernel_launch(void* const* d_in, const int* in_sizes, int n_in,
                              void* d_out, int out_size, void* d_ws, size_t ws_size,
                              hipStream_t stream) {
  const float* x      = (const float*)d_in[0];
  const float* w_attn = (const float*)d_in[1];
  const float* b_attn = (const float*)d_in[2];
  const float* w_proj = (const float*)d_in[3];
  const float* b_proj = (const float*)d_in[4];
  float* out = (float*)d_out;

  char* p = (char*)d_ws;
  unsigned short* xb  = (unsigned short*)p; p += (size_t)8192 * 768 * 2;
  unsigned short* waT = (unsigned short*)p; p += (size_t)2304 * 768 * 2;
  unsigned short* wpT = (unsigned short*)p; p += (size_t)768 * 768 * 2;
  unsigned short* qb  = (unsigned short*)p; p += (size_t)96 * 1024 * 64 * 2;
  unsigned short* kb  = (unsigned short*)p; p += (size_t)96 * 1024 * 64 * 2;
  unsigned short* vTb = (unsigned short*)p; p += (size_t)96 * 64 * 1024 * 2;
  unsigned short* yb  = (unsigned short*)p; p += (size_t)8192 * 768 * 2;

  cvt_bf16<<<6144, 256, 0, stream>>>(x, xb, 8192 * 768);
  transpose_cvt<<<dim3(36, 12), 256, 0, stream>>>(w_attn, waT, 768, 2304);
  transpose_cvt<<<dim3(12, 12), 256, 0, stream>>>(w_proj, wpT, 768, 768);
  gemm_qkv<<<dim3(64, 18), 256, 0, stream>>>(xb, waT, b_attn, qb, kb, vTb);
  attn<<<dim3(8, 96), 256, 0, stream>>>(qb, kb, vTb, yb);
  gemm_proj<<<dim3(64, 6), 256, 0, stream>>>(yb, wpT, b_proj, out);
}

// Round 2
// 226.647 us; speedup vs baseline: 1.2553x; 1.2553x over previous
//
#include <hip/hip_runtime.h>
#include <cstdint>
#include <cstddef>

typedef __attribute__((ext_vector_type(8))) short short8;     // 8 bf16 (4 VGPRs)
typedef __attribute__((ext_vector_type(4))) float f32x4;      // MFMA acc
typedef __attribute__((ext_vector_type(4))) unsigned short u16x4;

#define ASYNC16(gp, lp) \
  __builtin_amdgcn_global_load_lds((const __attribute__((address_space(1))) unsigned int*)(gp), \
                                   (__attribute__((address_space(3))) unsigned int*)(lp), 16, 0, 0)

__device__ __forceinline__ unsigned short f2b(float f) {
  union { float f; unsigned int u; } c; c.f = f;
  unsigned int u = c.u;
  return (unsigned short)((u + 0x7fffu + ((u >> 16) & 1u)) >> 16);
}

// ---------------- conversion kernels ----------------

__global__ void cvt_bf16(const float* __restrict__ X, unsigned short* __restrict__ Y, int n) {
  int i = (blockIdx.x * 256 + threadIdx.x) * 4;
  if (i < n) {
    const float* px = X + i;
    float a = px[0], b = px[1], c = px[2], d = px[3];
    u16x4 u;
    u[0] = f2b(a); u[1] = f2b(b); u[2] = f2b(c); u[3] = f2b(d);
    *(u16x4*)(Y + i) = u;
  }
}

// W [Kd][Nd] fp32 -> WT [Nd][Kd] bf16, 64x64 tiles
__global__ void transpose_cvt(const float* __restrict__ W, unsigned short* __restrict__ WT,
                              int Kd, int Nd) {
  __shared__ unsigned short Ts[64][65];
  int n0 = blockIdx.x * 64, k0 = blockIdx.y * 64;
  int tid = threadIdx.x;
  for (int idx = tid; idx < 4096; idx += 256) {
    int lr = idx >> 6, lc = idx & 63;
    Ts[lr][lc] = f2b(W[(size_t)(k0 + lr) * Nd + n0 + lc]);
  }
  __syncthreads();
  for (int idx = tid; idx < 4096; idx += 256) {
    int nr = idx >> 6, kc = idx & 63;
    WT[(size_t)(n0 + nr) * Kd + k0 + kc] = Ts[kc][nr];
  }
}

// ---------------- GEMM 1: qkv = x @ w_attn + b, scatter to q/k/vT ----------------

__global__ __launch_bounds__(256, 2) void gemm_qkv(
    const unsigned short* __restrict__ A,   // xb [8192][768]
    const unsigned short* __restrict__ Bt,  // waT [2304][768]
    const float* __restrict__ bias,         // [2304]
    unsigned short* __restrict__ q,         // [96][1024][64], pre-scaled by 0.125*log2(e)
    unsigned short* __restrict__ k,         // [96][1024][64]
    unsigned short* __restrict__ vT)        // [96][64][1024]
{
  __shared__ unsigned short As[128 * 32];
  __shared__ unsigned short Bs[128 * 32];
  const int tid = threadIdx.x;
  const int w = tid >> 6, lane = tid & 63;
  const int wm = w >> 1, wn = w & 1;
  const int lr = lane & 15, lq = lane >> 4;
  const int m0 = blockIdx.x * 128, n0 = blockIdx.y * 128;
  const f32x4 fzero = {0.f, 0.f, 0.f, 0.f};

  f32x4 acc[4][4];
  for (int i = 0; i < 4; ++i) for (int j = 0; j < 4; ++j) acc[i][j] = fzero;

  for (int kk0 = 0; kk0 < 768; kk0 += 32) {
    __syncthreads();
    for (int c = 0; c < 2; ++c) {
      int base = (c * 4 + w) * 1024;            // byte offset into 8 KB LDS tile
      int e = (base >> 1) + lane * 8;           // element index
      int row = e >> 5, kc = e & 31;
      ASYNC16(A  + (size_t)(m0 + row) * 768 + kk0 + kc, (char*)As + base);
      ASYNC16(Bt + (size_t)(n0 + row) * 768 + kk0 + kc, (char*)Bs + base);
    }
    __builtin_amdgcn_s_waitcnt(0);
    __syncthreads();

    short8 a[4], b[4];
    for (int i = 0; i < 4; ++i)
      a[i] = *(const short8*)(As + (wm * 64 + i * 16 + lr) * 32 + lq * 8);
    for (int j = 0; j < 4; ++j)
      b[j] = *(const short8*)(Bs + (wn * 64 + j * 16 + lr) * 32 + lq * 8);
    for (int i = 0; i < 4; ++i)
      for (int j = 0; j < 4; ++j)
        acc[i][j] = __builtin_amdgcn_mfma_f32_16x16x32_bf16(a[i], b[j], acc[i][j], 0, 0, 0);
  }

  // epilogue: each 128-col tile lies entirely in one of q/k/v
  const int colbase = n0 + wn * 64;
  const int sec = colbase / 768;                // 0=q, 1=k, 2=v (block-uniform)
  const float QSCALE = 0.18033688011112042f;    // 0.125 * log2(e)
  for (int j = 0; j < 4; ++j) {
    int col = colbase + j * 16 + lr;
    int cc = col - sec * 768;
    int h = cc >> 6, d = cc & 63;
    float bv = bias[col];
    for (int i = 0; i < 4; ++i) {
      int row0 = m0 + wm * 64 + i * 16 + lq * 4;
      int bidx = row0 >> 10, t0 = row0 & 1023;
      int bh = bidx * 12 + h;
      if (sec == 0) {
        for (int r = 0; r < 4; ++r)
          q[((size_t)bh * 1024 + t0 + r) * 64 + d] = f2b((acc[i][j][r] + bv) * QSCALE);
      } else if (sec == 1) {
        for (int r = 0; r < 4; ++r)
          k[((size_t)bh * 1024 + t0 + r) * 64 + d] = f2b(acc[i][j][r] + bv);
      } else {
        u16x4 pv;
        pv[0] = f2b(acc[i][j][0] + bv);
        pv[1] = f2b(acc[i][j][1] + bv);
        pv[2] = f2b(acc[i][j][2] + bv);
        pv[3] = f2b(acc[i][j][3] + bv);
        *(u16x4*)(vT + ((size_t)bh * 64 + d) * 1024 + t0) = pv;
      }
    }
  }
}

// ---------------- flash attention (no online-softmax: scores bounded, exp2 safe) ----
// grid 768: block g = (qp = g/96, bh = g%96); processes q-tiles qp and 15-qp
// (64 rows each) -> every block does exactly 17 k-tile units. 2 waves x 32 rows.

__global__ __launch_bounds__(128, 2) void attn(
    const unsigned short* __restrict__ q,
    const unsigned short* __restrict__ kk,
    const unsigned short* __restrict__ vT,
    unsigned short* __restrict__ y)         // [8192][768]
{
  __shared__ unsigned short Qs[64 * 72];    // stride 72: 2-way bank alias (free)
  __shared__ unsigned short Ks[64 * 72];
  __shared__ unsigned short Vt[64 * 72];    // [d][t]
  __shared__ unsigned short Ps[2 * 32 * 72];

  const int tid = threadIdx.x;
  const int w = tid >> 6, lane = tid & 63;
  const int lr = lane & 15, lq = lane >> 4;
  const int g = blockIdx.x;
  const int bh = g % 96;
  const int qp = g / 96;
  const int b = bh / 12, h = bh - b * 12;
  const f32x4 fzero = {0.f, 0.f, 0.f, 0.f};

  unsigned short* Pw = Ps + w * 32 * 72;

  for (int half = 0; half < 2; ++half) {
    const int qt = half ? (15 - qp) : qp;
    const int q0 = qt * 64;

    __syncthreads();                        // prior tile's reads complete
    const unsigned short* qptr = q + ((size_t)bh * 1024 + q0) * 64;
    for (int c = tid; c < 512; c += 128)
      *(short8*)(Qs + (c >> 3) * 72 + (c & 7) * 8) = *(const short8*)(qptr + (size_t)c * 8);

    f32x4 o[2][4];
    float l_s[2][4];
    for (int i = 0; i < 2; ++i) for (int jd = 0; jd < 4; ++jd) o[i][jd] = fzero;
    for (int i = 0; i < 2; ++i) for (int r = 0; r < 4; ++r) l_s[i][r] = 0.0f;

    for (int kt = 0; kt <= qt; ++kt) {
      const int kt0 = kt * 64;
      __syncthreads();                      // previous iteration's LDS reads done
      const unsigned short* kptr = kk + ((size_t)bh * 1024 + kt0) * 64;
      for (int c = tid; c < 512; c += 128)
        *(short8*)(Ks + (c >> 3) * 72 + (c & 7) * 8) = *(const short8*)(kptr + (size_t)c * 8);
      const unsigned short* vptr = vT + (size_t)bh * 65536 + kt0;
      for (int c = tid; c < 512; c += 128)
        *(short8*)(Vt + (c >> 3) * 72 + (c & 7) * 8) =
            *(const short8*)(vptr + (size_t)(c >> 3) * 1024 + (c & 7) * 8);
      __syncthreads();

      // S = Q K^T (pre-scaled by 0.125*log2e in q)
      f32x4 s[2][4];
      for (int i = 0; i < 2; ++i) for (int j = 0; j < 4; ++j) s[i][j] = fzero;
      for (int ks = 0; ks < 2; ++ks) {
        short8 aq[2], bk[4];
        for (int i = 0; i < 2; ++i)
          aq[i] = *(const short8*)(Qs + (w * 32 + i * 16 + lr) * 72 + ks * 32 + lq * 8);
        for (int j = 0; j < 4; ++j)
          bk[j] = *(const short8*)(Ks + (j * 16 + lr) * 72 + ks * 32 + lq * 8);
        for (int i = 0; i < 2; ++i)
          for (int j = 0; j < 4; ++j)
            s[i][j] = __builtin_amdgcn_mfma_f32_16x16x32_bf16(aq[i], bk[j], s[i][j], 0, 0, 0);
      }
      if (kt == qt) {                       // diagonal tile: causal mask
        for (int i = 0; i < 2; ++i) {
          int rowt = w * 32 + i * 16 + lq * 4;
          for (int j = 0; j < 4; ++j) {
            int colt = j * 16 + lr;
            for (int r = 0; r < 4; ++r)
              if (colt > rowt + r) s[i][j][r] = -1e30f;
          }
        }
      }
      // p = exp2(s); accumulate l per-lane; stash P in LDS (C-layout -> A-layout)
      for (int i = 0; i < 2; ++i)
        for (int r = 0; r < 4; ++r) {
          int prow = (i * 16 + lq * 4 + r) * 72;
          float acc = 0.0f;
          for (int j = 0; j < 4; ++j) {
            float p = __builtin_amdgcn_exp2f(s[i][j][r]);
            acc += p;
            Pw[prow + j * 16 + lr] = f2b(p);
          }
          l_s[i][r] += acc;
        }
      // O += P V  (same-wave DS ops are in-order; compiler emits lgkm waits)
      for (int ks = 0; ks < 2; ++ks) {
        short8 ap[2], bv[4];
        for (int i = 0; i < 2; ++i)
          ap[i] = *(const short8*)(Pw + (i * 16 + lr) * 72 + ks * 32 + lq * 8);
        for (int jd = 0; jd < 4; ++jd)
          bv[jd] = *(const short8*)(Vt + (jd * 16 + lr) * 72 + ks * 32 + lq * 8);
        for (int i = 0; i < 2; ++i)
          for (int jd = 0; jd < 4; ++jd)
            o[i][jd] = __builtin_amdgcn_mfma_f32_16x16x32_bf16(ap[i], bv[jd], o[i][jd], 0, 0, 0);
      }
    }

    // epilogue: reduce l across the 16 col-lanes, scale, store
    for (int i = 0; i < 2; ++i)
      for (int r = 0; r < 4; ++r) {
        float lv = l_s[i][r];
        for (int off = 1; off < 16; off <<= 1)
          lv += __shfl_xor(lv, off, 16);
        l_s[i][r] = 1.0f / lv;
      }
    for (int i = 0; i < 2; ++i) {
      int t = q0 + w * 32 + i * 16 + lq * 4;
      for (int jd = 0; jd < 4; ++jd) {
        int d = jd * 16 + lr;
        for (int r = 0; r < 4; ++r)
          y[((size_t)b * 1024 + t + r) * 768 + h * 64 + d] = f2b(o[i][jd][r] * l_s[i][r]);
      }
    }
  }
}

// ---------------- GEMM 2: out = y @ w_proj + b ----------------

__global__ __launch_bounds__(256, 2) void gemm_proj(
    const unsigned short* __restrict__ A,   // y [8192][768]
    const unsigned short* __restrict__ Bt,  // wpT [768][768]
    const float* __restrict__ bias,         // [768]
    float* __restrict__ out)                // [8192][768] fp32
{
  __shared__ unsigned short As[128 * 32];
  __shared__ unsigned short Bs[128 * 32];
  const int tid = threadIdx.x;
  const int w = tid >> 6, lane = tid & 63;
  const int wm = w >> 1, wn = w & 1;
  const int lr = lane & 15, lq = lane >> 4;
  const int m0 = blockIdx.x * 128, n0 = blockIdx.y * 128;
  const f32x4 fzero = {0.f, 0.f, 0.f, 0.f};

  f32x4 acc[4][4];
  for (int i = 0; i < 4; ++i) for (int j = 0; j < 4; ++j) acc[i][j] = fzero;

  for (int kk0 = 0; kk0 < 768; kk0 += 32) {
    __syncthreads();
    for (int c = 0; c < 2; ++c) {
      int base = (c * 4 + w) * 1024;
      int e = (base >> 1) + lane * 8;
      int row = e >> 5, kc = e & 31;
      ASYNC16(A  + (size_t)(m0 + row) * 768 + kk0 + kc, (char*)As + base);
      ASYNC16(Bt + (size_t)(n0 + row) * 768 + kk0 + kc, (char*)Bs + base);
    }
    __builtin_amdgcn_s_waitcnt(0);
    __syncthreads();

    short8 a[4], b[4];
    for (int i = 0; i < 4; ++i)
      a[i] = *(const short8*)(As + (wm * 64 + i * 16 + lr) * 32 + lq * 8);
    for (int j = 0; j < 4; ++j)
      b[j] = *(const short8*)(Bs + (wn * 64 + j * 16 + lr) * 32 + lq * 8);
    for (int i = 0; i < 4; ++i)
      for (int j = 0; j < 4; ++j)
        acc[i][j] = __builtin_amdgcn_mfma_f32_16x16x32_bf16(a[i], b[j], acc[i][j], 0, 0, 0);
  }

  for (int j = 0; j < 4; ++j) {
    int col = n0 + wn * 64 + j * 16 + lr;
    float bv = bias[col];
    for (int i = 0; i < 4; ++i) {
      int row0 = m0 + wm * 64 + i * 16 + lq * 4;
      for (int r = 0; r < 4; ++r)
        out[(size_t)(row0 + r) * 768 + col] = acc[i][j][r] + bv;
    }
  }
}

// ---------------- launch ----------------

extern "C" void kernel_launch(void* const* d_in, const int* in_sizes, int n_in,
                              void* d_out, int out_size, void* d_ws, size_t ws_size,
                              hipStream_t stream) {
  const float* x      = (const float*)d_in[0];
  const float* w_attn = (const float*)d_in[1];
  const float* b_attn = (const float*)d_in[2];
  const float* w_proj = (const float*)d_in[3];
  const float* b_proj = (const float*)d_in[4];
  float* out = (float*)d_out;

  char* p = (char*)d_ws;
  unsigned short* xb  = (unsigned short*)p; p += (size_t)8192 * 768 * 2;
  unsigned short* waT = (unsigned short*)p; p += (size_t)2304 * 768 * 2;
  unsigned short* wpT = (unsigned short*)p; p += (size_t)768 * 768 * 2;
  unsigned short* qb  = (unsigned short*)p; p += (size_t)96 * 1024 * 64 * 2;
  unsigned short* kb  = (unsigned short*)p; p += (size_t)96 * 1024 * 64 * 2;
  unsigned short* vTb = (unsigned short*)p; p += (size_t)96 * 64 * 1024 * 2;
  unsigned short* yb  = (unsigned short*)p; p += (size_t)8192 * 768 * 2;

  cvt_bf16<<<6144, 256, 0, stream>>>(x, xb, 8192 * 768);
  transpose_cvt<<<dim3(36, 12), 256, 0, stream>>>(w_attn, waT, 768, 2304);
  transpose_cvt<<<dim3(12, 12), 256, 0, stream>>>(w_proj, wpT, 768, 768);
  gemm_qkv<<<dim3(64, 18), 256, 0, stream>>>(xb, waT, b_attn, qb, kb, vTb);
  attn<<<768, 128, 0, stream>>>(qb, kb, vTb, yb);
  gemm_proj<<<dim3(64, 6), 256, 0, stream>>>(yb, wpT, b_proj, out);
}

// Round 3
// 196.101 us; speedup vs baseline: 1.4508x; 1.1558x over previous
//
#include <hip/hip_runtime.h>
#include <cstdint>
#include <cstddef>

typedef __attribute__((ext_vector_type(8))) short short8;     // 8 bf16 (4 VGPRs)
typedef __attribute__((ext_vector_type(4))) float f32x4;      // MFMA acc
typedef __attribute__((ext_vector_type(4))) unsigned short u16x4;

#define ASYNC16(gp, lp) \
  __builtin_amdgcn_global_load_lds((const __attribute__((address_space(1))) unsigned int*)(gp), \
                                   (__attribute__((address_space(3))) unsigned int*)(lp), 16, 0, 0)

__device__ __forceinline__ unsigned short f2b(float f) {
  union { float f; unsigned int u; } c; c.f = f;
  unsigned int u = c.u;
  return (unsigned short)((u + 0x7fffu + ((u >> 16) & 1u)) >> 16);
}

// ---------------- conversion kernels ----------------

__global__ void cvt_bf16(const float* __restrict__ X, unsigned short* __restrict__ Y, int n) {
  int i = (blockIdx.x * 256 + threadIdx.x) * 4;
  if (i < n) {
    const float* px = X + i;
    float a = px[0], b = px[1], c = px[2], d = px[3];
    u16x4 u;
    u[0] = f2b(a); u[1] = f2b(b); u[2] = f2b(c); u[3] = f2b(d);
    *(u16x4*)(Y + i) = u;
  }
}

// W [Kd][Nd] fp32 -> WT [Nd][Kd] bf16, 64x64 tiles
__global__ void transpose_cvt(const float* __restrict__ W, unsigned short* __restrict__ WT,
                              int Kd, int Nd) {
  __shared__ unsigned short Ts[64][65];
  int n0 = blockIdx.x * 64, k0 = blockIdx.y * 64;
  int tid = threadIdx.x;
  for (int idx = tid; idx < 4096; idx += 256) {
    int lr = idx >> 6, lc = idx & 63;
    Ts[lr][lc] = f2b(W[(size_t)(k0 + lr) * Nd + n0 + lc]);
  }
  __syncthreads();
  for (int idx = tid; idx < 4096; idx += 256) {
    int nr = idx >> 6, kc = idx & 63;
    WT[(size_t)(n0 + nr) * Kd + k0 + kc] = Ts[kc][nr];
  }
}

// ---------------- GEMM 1: qkv = x @ w_attn + b, scatter to q/k/vT ----------------

__global__ __launch_bounds__(256, 2) void gemm_qkv(
    const unsigned short* __restrict__ A,   // xb [8192][768]
    const unsigned short* __restrict__ Bt,  // waT [2304][768]
    const float* __restrict__ bias,         // [2304]
    unsigned short* __restrict__ q,         // [96][1024][64], pre-scaled by 0.125*log2(e)
    unsigned short* __restrict__ k,         // [96][1024][64]
    unsigned short* __restrict__ vT)        // [96][64][1024]
{
  __shared__ unsigned short As[128 * 32];
  __shared__ unsigned short Bs[128 * 32];
  const int tid = threadIdx.x;
  const int w = tid >> 6, lane = tid & 63;
  const int wm = w >> 1, wn = w & 1;
  const int lr = lane & 15, lq = lane >> 4;
  const int m0 = blockIdx.x * 128, n0 = blockIdx.y * 128;
  const f32x4 fzero = {0.f, 0.f, 0.f, 0.f};

  f32x4 acc[4][4];
  for (int i = 0; i < 4; ++i) for (int j = 0; j < 4; ++j) acc[i][j] = fzero;

  for (int kk0 = 0; kk0 < 768; kk0 += 32) {
    __syncthreads();
    for (int c = 0; c < 2; ++c) {
      int base = (c * 4 + w) * 1024;            // byte offset into 8 KB LDS tile
      int e = (base >> 1) + lane * 8;           // element index
      int row = e >> 5, kc = e & 31;
      ASYNC16(A  + (size_t)(m0 + row) * 768 + kk0 + kc, (char*)As + base);
      ASYNC16(Bt + (size_t)(n0 + row) * 768 + kk0 + kc, (char*)Bs + base);
    }
    __builtin_amdgcn_s_waitcnt(0);
    __syncthreads();

    short8 a[4], b[4];
    for (int i = 0; i < 4; ++i)
      a[i] = *(const short8*)(As + (wm * 64 + i * 16 + lr) * 32 + lq * 8);
    for (int j = 0; j < 4; ++j)
      b[j] = *(const short8*)(Bs + (wn * 64 + j * 16 + lr) * 32 + lq * 8);
    for (int i = 0; i < 4; ++i)
      for (int j = 0; j < 4; ++j)
        acc[i][j] = __builtin_amdgcn_mfma_f32_16x16x32_bf16(a[i], b[j], acc[i][j], 0, 0, 0);
  }

  // epilogue: each 128-col tile lies entirely in one of q/k/v
  const int colbase = n0 + wn * 64;
  const int sec = colbase / 768;                // 0=q, 1=k, 2=v (block-uniform)
  const float QSCALE = 0.18033688011112042f;    // 0.125 * log2(e)
  for (int j = 0; j < 4; ++j) {
    int col = colbase + j * 16 + lr;
    int cc = col - sec * 768;
    int h = cc >> 6, d = cc & 63;
    float bv = bias[col];
    for (int i = 0; i < 4; ++i) {
      int row0 = m0 + wm * 64 + i * 16 + lq * 4;
      int bidx = row0 >> 10, t0 = row0 & 1023;
      int bh = bidx * 12 + h;
      if (sec == 0) {
        for (int r = 0; r < 4; ++r)
          q[((size_t)bh * 1024 + t0 + r) * 64 + d] = f2b((acc[i][j][r] + bv) * QSCALE);
      } else if (sec == 1) {
        for (int r = 0; r < 4; ++r)
          k[((size_t)bh * 1024 + t0 + r) * 64 + d] = f2b(acc[i][j][r] + bv);
      } else {
        u16x4 pv;
        pv[0] = f2b(acc[i][j][0] + bv);
        pv[1] = f2b(acc[i][j][1] + bv);
        pv[2] = f2b(acc[i][j][2] + bv);
        pv[3] = f2b(acc[i][j][3] + bv);
        *(u16x4*)(vT + ((size_t)bh * 64 + d) * 1024 + t0) = pv;
      }
    }
  }
}

// ---------------- flash attention (no online-softmax: scores bounded, exp2 safe) ----
// grid 768: block g = (qp = g/96, bh = g%96); processes q-tiles qp and 15-qp
// (64 rows each) -> every block does exactly 17 k-tile units.
// 4 waves x 16 q-rows each; K/V software-pipelined through registers.

__global__ __launch_bounds__(256, 2) void attn(
    const unsigned short* __restrict__ q,
    const unsigned short* __restrict__ kk,
    const unsigned short* __restrict__ vT,
    unsigned short* __restrict__ y)         // [8192][768]
{
  __shared__ unsigned short Qs[64 * 72];    // stride 72: 2-way bank alias (free)
  __shared__ unsigned short Ks[64 * 72];
  __shared__ unsigned short Vt[64 * 72];    // [d][t]
  __shared__ unsigned short Ps[4 * 16 * 72];

  const int tid = threadIdx.x;
  const int w = tid >> 6, lane = tid & 63;
  const int lr = lane & 15, lq = lane >> 4;
  const int g = blockIdx.x;
  const int bh = g % 96;
  const int qp = g / 96;
  const int b = bh / 12, h = bh - b * 12;
  const f32x4 fzero = {0.f, 0.f, 0.f, 0.f};

  unsigned short* Pw = Ps + w * 16 * 72;
  const unsigned short* kbase = kk + (size_t)bh * 65536;
  const unsigned short* vbase = vT + (size_t)bh * 65536;

  const int c0 = tid, c1 = tid + 256;       // staging element-chunk ids (row=c>>3)
  short8 kreg[2], vreg[2];

  for (int half = 0; half < 2; ++half) {
    const int qt = half ? (15 - qp) : qp;
    const int q0 = qt * 64;

    __syncthreads();                        // prior half's LDS reads complete
    {
      const unsigned short* qptr = q + ((size_t)bh * 1024 + q0) * 64;
      short8 q0r = *(const short8*)(qptr + (size_t)c0 * 8);
      short8 q1r = *(const short8*)(qptr + (size_t)c1 * 8);
      *(short8*)(Qs + (c0 >> 3) * 72 + (c0 & 7) * 8) = q0r;
      *(short8*)(Qs + (c1 >> 3) * 72 + (c1 & 7) * 8) = q1r;
    }
    // prefetch kt = 0
    kreg[0] = *(const short8*)(kbase + (size_t)c0 * 8);
    kreg[1] = *(const short8*)(kbase + (size_t)c1 * 8);
    vreg[0] = *(const short8*)(vbase + (size_t)(c0 >> 3) * 1024 + (c0 & 7) * 8);
    vreg[1] = *(const short8*)(vbase + (size_t)(c1 >> 3) * 1024 + (c1 & 7) * 8);

    f32x4 o[4];
    float l_s[4];
    for (int jd = 0; jd < 4; ++jd) o[jd] = fzero;
    for (int r = 0; r < 4; ++r) l_s[r] = 0.0f;

    for (int kt = 0; kt <= qt; ++kt) {
      __syncthreads();                      // prev iter's LDS reads done (+Q writes visible)
      *(short8*)(Ks + (c0 >> 3) * 72 + (c0 & 7) * 8) = kreg[0];
      *(short8*)(Ks + (c1 >> 3) * 72 + (c1 & 7) * 8) = kreg[1];
      *(short8*)(Vt + (c0 >> 3) * 72 + (c0 & 7) * 8) = vreg[0];
      *(short8*)(Vt + (c1 >> 3) * 72 + (c1 & 7) * 8) = vreg[1];
      __syncthreads();
      if (kt < qt) {                        // prefetch next tile; overlaps compute below
        const unsigned short* kp = kbase + (size_t)(kt + 1) * 4096;
        const unsigned short* vp = vbase + (size_t)(kt + 1) * 64;
        kreg[0] = *(const short8*)(kp + (size_t)c0 * 8);
        kreg[1] = *(const short8*)(kp + (size_t)c1 * 8);
        vreg[0] = *(const short8*)(vp + (size_t)(c0 >> 3) * 1024 + (c0 & 7) * 8);
        vreg[1] = *(const short8*)(vp + (size_t)(c1 >> 3) * 1024 + (c1 & 7) * 8);
      }

      // S = Q K^T (q pre-scaled by 0.125*log2e)
      f32x4 s[4];
      for (int j = 0; j < 4; ++j) s[j] = fzero;
      for (int ks = 0; ks < 2; ++ks) {
        short8 aq = *(const short8*)(Qs + (w * 16 + lr) * 72 + ks * 32 + lq * 8);
        short8 bk[4];
        for (int j = 0; j < 4; ++j)
          bk[j] = *(const short8*)(Ks + (j * 16 + lr) * 72 + ks * 32 + lq * 8);
        for (int j = 0; j < 4; ++j)
          s[j] = __builtin_amdgcn_mfma_f32_16x16x32_bf16(aq, bk[j], s[j], 0, 0, 0);
      }
      if (kt == qt) {                       // diagonal tile: causal mask
        int rowt = w * 16 + lq * 4;
        for (int j = 0; j < 4; ++j) {
          int colt = j * 16 + lr;
          for (int r = 0; r < 4; ++r)
            if (colt > rowt + r) s[j][r] = -1e30f;
        }
      }
      // p = exp2(s); accumulate l per-lane; stash P (C-layout -> A-layout via LDS)
      for (int r = 0; r < 4; ++r) {
        int prow = (lq * 4 + r) * 72;
        float acc = 0.0f;
        for (int j = 0; j < 4; ++j) {
          float p = __builtin_amdgcn_exp2f(s[j][r]);
          acc += p;
          union { float f; unsigned int u; } cv; cv.f = p;
          Pw[prow + j * 16 + lr] = (unsigned short)((cv.u + 0x8000u) >> 16);
        }
        l_s[r] += acc;
      }
      // O += P V (same-wave DS in-order; compiler emits lgkm waits)
      for (int ks = 0; ks < 2; ++ks) {
        short8 ap = *(const short8*)(Pw + lr * 72 + ks * 32 + lq * 8);
        short8 bv[4];
        for (int jd = 0; jd < 4; ++jd)
          bv[jd] = *(const short8*)(Vt + (jd * 16 + lr) * 72 + ks * 32 + lq * 8);
        for (int jd = 0; jd < 4; ++jd)
          o[jd] = __builtin_amdgcn_mfma_f32_16x16x32_bf16(ap, bv[jd], o[jd], 0, 0, 0);
      }
    }

    // epilogue: reduce l across the 16 col-lanes, scale, store
    for (int r = 0; r < 4; ++r) {
      float lv = l_s[r];
      for (int off = 1; off < 16; off <<= 1)
        lv += __shfl_xor(lv, off, 16);
      l_s[r] = 1.0f / lv;
    }
    int t = q0 + w * 16 + lq * 4;
    for (int jd = 0; jd < 4; ++jd) {
      int d = jd * 16 + lr;
      for (int r = 0; r < 4; ++r)
        y[((size_t)b * 1024 + t + r) * 768 + h * 64 + d] = f2b(o[jd][r] * l_s[r]);
    }
  }
}

// ---------------- GEMM 2: out = y @ w_proj + b ----------------

__global__ __launch_bounds__(256, 2) void gemm_proj(
    const unsigned short* __restrict__ A,   // y [8192][768]
    const unsigned short* __restrict__ Bt,  // wpT [768][768]
    const float* __restrict__ bias,         // [768]
    float* __restrict__ out)                // [8192][768] fp32
{
  __shared__ unsigned short As[128 * 32];
  __shared__ unsigned short Bs[128 * 32];
  const int tid = threadIdx.x;
  const int w = tid >> 6, lane = tid & 63;
  const int wm = w >> 1, wn = w & 1;
  const int lr = lane & 15, lq = lane >> 4;
  const int m0 = blockIdx.x * 128, n0 = blockIdx.y * 128;
  const f32x4 fzero = {0.f, 0.f, 0.f, 0.f};

  f32x4 acc[4][4];
  for (int i = 0; i < 4; ++i) for (int j = 0; j < 4; ++j) acc[i][j] = fzero;

  for (int kk0 = 0; kk0 < 768; kk0 += 32) {
    __syncthreads();
    for (int c = 0; c < 2; ++c) {
      int base = (c * 4 + w) * 1024;
      int e = (base >> 1) + lane * 8;
      int row = e >> 5, kc = e & 31;
      ASYNC16(A  + (size_t)(m0 + row) * 768 + kk0 + kc, (char*)As + base);
      ASYNC16(Bt + (size_t)(n0 + row) * 768 + kk0 + kc, (char*)Bs + base);
    }
    __builtin_amdgcn_s_waitcnt(0);
    __syncthreads();

    short8 a[4], b[4];
    for (int i = 0; i < 4; ++i)
      a[i] = *(const short8*)(As + (wm * 64 + i * 16 + lr) * 32 + lq * 8);
    for (int j = 0; j < 4; ++j)
      b[j] = *(const short8*)(Bs + (wn * 64 + j * 16 + lr) * 32 + lq * 8);
    for (int i = 0; i < 4; ++i)
      for (int j = 0; j < 4; ++j)
        acc[i][j] = __builtin_amdgcn_mfma_f32_16x16x32_bf16(a[i], b[j], acc[i][j], 0, 0, 0);
  }

  for (int j = 0; j < 4; ++j) {
    int col = n0 + wn * 64 + j * 16 + lr;
    float bv = bias[col];
    for (int i = 0; i < 4; ++i) {
      int row0 = m0 + wm * 64 + i * 16 + lq * 4;
      for (int r = 0; r < 4; ++r)
        out[(size_t)(row0 + r) * 768 + col] = acc[i][j][r] + bv;
    }
  }
}

// ---------------- launch ----------------

extern "C" void kernel_launch(void* const* d_in, const int* in_sizes, int n_in,
                              void* d_out, int out_size, void* d_ws, size_t ws_size,
                              hipStream_t stream) {
  const float* x      = (const float*)d_in[0];
  const float* w_attn = (const float*)d_in[1];
  const float* b_attn = (const float*)d_in[2];
  const float* w_proj = (const float*)d_in[3];
  const float* b_proj = (const float*)d_in[4];
  float* out = (float*)d_out;

  char* p = (char*)d_ws;
  unsigned short* xb  = (unsigned short*)p; p += (size_t)8192 * 768 * 2;
  unsigned short* waT = (unsigned short*)p; p += (size_t)2304 * 768 * 2;
  unsigned short* wpT = (unsigned short*)p; p += (size_t)768 * 768 * 2;
  unsigned short* qb  = (unsigned short*)p; p += (size_t)96 * 1024 * 64 * 2;
  unsigned short* kb  = (unsigned short*)p; p += (size_t)96 * 1024 * 64 * 2;
  unsigned short* vTb = (unsigned short*)p; p += (size_t)96 * 64 * 1024 * 2;
  unsigned short* yb  = (unsigned short*)p; p += (size_t)8192 * 768 * 2;

  cvt_bf16<<<6144, 256, 0, stream>>>(x, xb, 8192 * 768);
  transpose_cvt<<<dim3(36, 12), 256, 0, stream>>>(w_attn, waT, 768, 2304);
  transpose_cvt<<<dim3(12, 12), 256, 0, stream>>>(w_proj, wpT, 768, 768);
  gemm_qkv<<<dim3(64, 18), 256, 0, stream>>>(xb, waT, b_attn, qb, kb, vTb);
  attn<<<768, 256, 0, stream>>>(qb, kb, vTb, yb);
  gemm_proj<<<dim3(64, 6), 256, 0, stream>>>(yb, wpT, b_proj, out);
}

// Round 4
// 194.581 us; speedup vs baseline: 1.4622x; 1.0078x over previous
//
#include <hip/hip_runtime.h>
#include <cstdint>
#include <cstddef>

typedef __attribute__((ext_vector_type(8))) short short8;     // 8 bf16 (4 VGPRs)
typedef __attribute__((ext_vector_type(4))) float f32x4;      // MFMA acc
typedef __attribute__((ext_vector_type(4))) unsigned short u16x4;

#define ASYNC16(gp, lp) \
  __builtin_amdgcn_global_load_lds((const __attribute__((address_space(1))) unsigned int*)(gp), \
                                   (__attribute__((address_space(3))) unsigned int*)(lp), 16, 0, 0)

__device__ __forceinline__ unsigned short f2b(float f) {
  union { float f; unsigned int u; } c; c.f = f;
  unsigned int u = c.u;
  return (unsigned short)((u + 0x7fffu + ((u >> 16) & 1u)) >> 16);
}

// ---------------- conversion kernels ----------------

__global__ void cvt_bf16(const float* __restrict__ X, unsigned short* __restrict__ Y, int n) {
  int i = (blockIdx.x * 256 + threadIdx.x) * 4;
  if (i < n) {
    const float* px = X + i;
    float a = px[0], b = px[1], c = px[2], d = px[3];
    u16x4 u;
    u[0] = f2b(a); u[1] = f2b(b); u[2] = f2b(c); u[3] = f2b(d);
    *(u16x4*)(Y + i) = u;
  }
}

// W [Kd][Nd] fp32 -> WT [Nd][Kd] bf16, 64x64 tiles
__global__ void transpose_cvt(const float* __restrict__ W, unsigned short* __restrict__ WT,
                              int Kd, int Nd) {
  __shared__ unsigned short Ts[64][65];
  int n0 = blockIdx.x * 64, k0 = blockIdx.y * 64;
  int tid = threadIdx.x;
  for (int idx = tid; idx < 4096; idx += 256) {
    int lr = idx >> 6, lc = idx & 63;
    Ts[lr][lc] = f2b(W[(size_t)(k0 + lr) * Nd + n0 + lc]);
  }
  __syncthreads();
  for (int idx = tid; idx < 4096; idx += 256) {
    int nr = idx >> 6, kc = idx & 63;
    WT[(size_t)(n0 + nr) * Kd + k0 + kc] = Ts[kc][nr];
  }
}

// ---------------- GEMM 1: qkv = x @ w_attn + b, scatter to q/k/vT ----------------
// Double-buffered LDS, raw s_barrier + fine vmcnt(4): prefetch stays in flight
// across the barrier (AITER pattern) instead of __syncthreads()'s vmcnt(0) drain.

__global__ __launch_bounds__(256, 4) void gemm_qkv(
    const unsigned short* __restrict__ A,   // xb [8192][768]
    const unsigned short* __restrict__ Bt,  // waT [2304][768]
    const float* __restrict__ bias,         // [2304]
    unsigned short* __restrict__ q,         // [96][1024][64], pre-scaled by 0.125*log2(e)
    unsigned short* __restrict__ k,         // [96][1024][64]
    unsigned short* __restrict__ vT)        // [96][64][1024]
{
  __shared__ unsigned short As[2 * 4096];   // 2 x 8KB
  __shared__ unsigned short Bs[2 * 4096];
  const int tid = threadIdx.x;
  const int w = tid >> 6, lane = tid & 63;
  const int wm = w >> 1, wn = w & 1;
  const int lr = lane & 15, lq = lane >> 4;
  const int m0 = blockIdx.x * 128, n0 = blockIdx.y * 128;
  const f32x4 fzero = {0.f, 0.f, 0.f, 0.f};

  f32x4 acc[4][4];
  for (int i = 0; i < 4; ++i) for (int j = 0; j < 4; ++j) acc[i][j] = fzero;

  // staging geometry (per c-chunk, wave-uniform LDS base; lane offset = lane*16)
  int sbase[2], srow[2], skc[2];
  for (int c = 0; c < 2; ++c) {
    sbase[c] = (c * 4 + w) * 1024;
    int e = (sbase[c] >> 1) + lane * 8;
    srow[c] = e >> 5; skc[c] = e & 31;
  }

  // prologue: issue tile 0 into buf 0
  for (int c = 0; c < 2; ++c) {
    ASYNC16(A  + (size_t)(m0 + srow[c]) * 768 + skc[c], (char*)As + sbase[c]);
    ASYNC16(Bt + (size_t)(n0 + srow[c]) * 768 + skc[c], (char*)Bs + sbase[c]);
  }

  for (int kt = 0; kt < 24; ++kt) {
    const int cur = kt & 1;
    asm volatile("s_barrier" ::: "memory");           // all waves done reading buf cur^1
    if (kt < 23) {
      const int kk0 = (kt + 1) * 32;
      const int dst = (cur ^ 1) * 8192;               // byte offset of next buffer
      for (int c = 0; c < 2; ++c) {
        ASYNC16(A  + (size_t)(m0 + srow[c]) * 768 + kk0 + skc[c], (char*)As + dst + sbase[c]);
        ASYNC16(Bt + (size_t)(n0 + srow[c]) * 768 + kk0 + skc[c], (char*)Bs + dst + sbase[c]);
      }
      asm volatile("s_waitcnt vmcnt(4)" ::: "memory"); // tile kt done; next 4 stay in flight
    } else {
      asm volatile("s_waitcnt vmcnt(0)" ::: "memory");
    }
    asm volatile("s_barrier" ::: "memory");           // whole tile kt now in LDS

    const unsigned short* Ar = As + cur * 4096;
    const unsigned short* Br = Bs + cur * 4096;
    short8 a[4], b[4];
    for (int i = 0; i < 4; ++i)
      a[i] = *(const short8*)(Ar + (wm * 64 + i * 16 + lr) * 32 + lq * 8);
    for (int j = 0; j < 4; ++j)
      b[j] = *(const short8*)(Br + (wn * 64 + j * 16 + lr) * 32 + lq * 8);
    for (int i = 0; i < 4; ++i)
      for (int j = 0; j < 4; ++j)
        acc[i][j] = __builtin_amdgcn_mfma_f32_16x16x32_bf16(a[i], b[j], acc[i][j], 0, 0, 0);
  }

  // epilogue: each 128-col tile lies entirely in one of q/k/v
  const int colbase = n0 + wn * 64;
  const int sec = colbase / 768;                // 0=q, 1=k, 2=v (block-uniform)
  const float QSCALE = 0.18033688011112042f;    // 0.125 * log2(e)
  for (int j = 0; j < 4; ++j) {
    int col = colbase + j * 16 + lr;
    int cc = col - sec * 768;
    int h = cc >> 6, d = cc & 63;
    float bv = bias[col];
    for (int i = 0; i < 4; ++i) {
      int row0 = m0 + wm * 64 + i * 16 + lq * 4;
      int bidx = row0 >> 10, t0 = row0 & 1023;
      int bh = bidx * 12 + h;
      if (sec == 0) {
        for (int r = 0; r < 4; ++r)
          q[((size_t)bh * 1024 + t0 + r) * 64 + d] = f2b((acc[i][j][r] + bv) * QSCALE);
      } else if (sec == 1) {
        for (int r = 0; r < 4; ++r)
          k[((size_t)bh * 1024 + t0 + r) * 64 + d] = f2b(acc[i][j][r] + bv);
      } else {
        u16x4 pv;
        pv[0] = f2b(acc[i][j][0] + bv);
        pv[1] = f2b(acc[i][j][1] + bv);
        pv[2] = f2b(acc[i][j][2] + bv);
        pv[3] = f2b(acc[i][j][3] + bv);
        *(u16x4*)(vT + ((size_t)bh * 64 + d) * 1024 + t0) = pv;
      }
    }
  }
}

// ---------------- flash attention (no online-softmax: scores bounded, exp2 safe) ----
// grid 768: block g = (qp = g/96, bh = g%96); processes q-tiles qp and 15-qp
// (64 rows each) -> every block does exactly 17 k-tile units.
// 4 waves x 16 q-rows each; K/V software-pipelined through registers.

__global__ __launch_bounds__(256, 2) void attn(
    const unsigned short* __restrict__ q,
    const unsigned short* __restrict__ kk,
    const unsigned short* __restrict__ vT,
    unsigned short* __restrict__ y)         // [8192][768]
{
  __shared__ unsigned short Qs[64 * 72];    // stride 72: 2-way bank alias (free)
  __shared__ unsigned short Ks[64 * 72];
  __shared__ unsigned short Vt[64 * 72];    // [d][t]
  __shared__ unsigned short Ps[4 * 16 * 72];

  const int tid = threadIdx.x;
  const int w = tid >> 6, lane = tid & 63;
  const int lr = lane & 15, lq = lane >> 4;
  const int g = blockIdx.x;
  const int bh = g % 96;
  const int qp = g / 96;
  const int b = bh / 12, h = bh - b * 12;
  const f32x4 fzero = {0.f, 0.f, 0.f, 0.f};

  unsigned short* Pw = Ps + w * 16 * 72;
  const unsigned short* kbase = kk + (size_t)bh * 65536;
  const unsigned short* vbase = vT + (size_t)bh * 65536;

  const int c0 = tid, c1 = tid + 256;       // staging element-chunk ids (row=c>>3)
  short8 kreg[2], vreg[2];

  for (int half = 0; half < 2; ++half) {
    const int qt = half ? (15 - qp) : qp;
    const int q0 = qt * 64;

    __syncthreads();                        // prior half's LDS reads complete
    {
      const unsigned short* qptr = q + ((size_t)bh * 1024 + q0) * 64;
      short8 q0r = *(const short8*)(qptr + (size_t)c0 * 8);
      short8 q1r = *(const short8*)(qptr + (size_t)c1 * 8);
      *(short8*)(Qs + (c0 >> 3) * 72 + (c0 & 7) * 8) = q0r;
      *(short8*)(Qs + (c1 >> 3) * 72 + (c1 & 7) * 8) = q1r;
    }
    // prefetch kt = 0
    kreg[0] = *(const short8*)(kbase + (size_t)c0 * 8);
    kreg[1] = *(const short8*)(kbase + (size_t)c1 * 8);
    vreg[0] = *(const short8*)(vbase + (size_t)(c0 >> 3) * 1024 + (c0 & 7) * 8);
    vreg[1] = *(const short8*)(vbase + (size_t)(c1 >> 3) * 1024 + (c1 & 7) * 8);

    f32x4 o[4];
    float l_s[4];
    for (int jd = 0; jd < 4; ++jd) o[jd] = fzero;
    for (int r = 0; r < 4; ++r) l_s[r] = 0.0f;

    for (int kt = 0; kt <= qt; ++kt) {
      __syncthreads();                      // prev iter's LDS reads done (+Q writes visible)
      *(short8*)(Ks + (c0 >> 3) * 72 + (c0 & 7) * 8) = kreg[0];
      *(short8*)(Ks + (c1 >> 3) * 72 + (c1 & 7) * 8) = kreg[1];
      *(short8*)(Vt + (c0 >> 3) * 72 + (c0 & 7) * 8) = vreg[0];
      *(short8*)(Vt + (c1 >> 3) * 72 + (c1 & 7) * 8) = vreg[1];
      __syncthreads();
      if (kt < qt) {                        // prefetch next tile; overlaps compute below
        const unsigned short* kp = kbase + (size_t)(kt + 1) * 4096;
        const unsigned short* vp = vbase + (size_t)(kt + 1) * 64;
        kreg[0] = *(const short8*)(kp + (size_t)c0 * 8);
        kreg[1] = *(const short8*)(kp + (size_t)c1 * 8);
        vreg[0] = *(const short8*)(vp + (size_t)(c0 >> 3) * 1024 + (c0 & 7) * 8);
        vreg[1] = *(const short8*)(vp + (size_t)(c1 >> 3) * 1024 + (c1 & 7) * 8);
      }

      // S = Q K^T (q pre-scaled by 0.125*log2e)
      f32x4 s[4];
      for (int j = 0; j < 4; ++j) s[j] = fzero;
      for (int ks = 0; ks < 2; ++ks) {
        short8 aq = *(const short8*)(Qs + (w * 16 + lr) * 72 + ks * 32 + lq * 8);
        short8 bk[4];
        for (int j = 0; j < 4; ++j)
          bk[j] = *(const short8*)(Ks + (j * 16 + lr) * 72 + ks * 32 + lq * 8);
        for (int j = 0; j < 4; ++j)
          s[j] = __builtin_amdgcn_mfma_f32_16x16x32_bf16(aq, bk[j], s[j], 0, 0, 0);
      }
      if (kt == qt) {                       // diagonal tile: causal mask
        int rowt = w * 16 + lq * 4;
        for (int j = 0; j < 4; ++j) {
          int colt = j * 16 + lr;
          for (int r = 0; r < 4; ++r)
            if (colt > rowt + r) s[j][r] = -1e30f;
        }
      }
      // p = exp2(s); accumulate l per-lane; stash P (C-layout -> A-layout via LDS)
      for (int r = 0; r < 4; ++r) {
        int prow = (lq * 4 + r) * 72;
        float acc = 0.0f;
        for (int j = 0; j < 4; ++j) {
          float p = __builtin_amdgcn_exp2f(s[j][r]);
          acc += p;
          union { float f; unsigned int u; } cv; cv.f = p;
          Pw[prow + j * 16 + lr] = (unsigned short)((cv.u + 0x8000u) >> 16);
        }
        l_s[r] += acc;
      }
      // O += P V (same-wave DS in-order; compiler emits lgkm waits)
      for (int ks = 0; ks < 2; ++ks) {
        short8 ap = *(const short8*)(Pw + lr * 72 + ks * 32 + lq * 8);
        short8 bv[4];
        for (int jd = 0; jd < 4; ++jd)
          bv[jd] = *(const short8*)(Vt + (jd * 16 + lr) * 72 + ks * 32 + lq * 8);
        for (int jd = 0; jd < 4; ++jd)
          o[jd] = __builtin_amdgcn_mfma_f32_16x16x32_bf16(ap, bv[jd], o[jd], 0, 0, 0);
      }
    }

    // epilogue: reduce l across the 16 col-lanes, scale, store
    for (int r = 0; r < 4; ++r) {
      float lv = l_s[r];
      for (int off = 1; off < 16; off <<= 1)
        lv += __shfl_xor(lv, off, 16);
      l_s[r] = 1.0f / lv;
    }
    int t = q0 + w * 16 + lq * 4;
    for (int jd = 0; jd < 4; ++jd) {
      int d = jd * 16 + lr;
      for (int r = 0; r < 4; ++r)
        y[((size_t)b * 1024 + t + r) * 768 + h * 64 + d] = f2b(o[jd][r] * l_s[r]);
    }
  }
}

// ---------------- GEMM 2: out = y @ w_proj + b (same pipelined structure) --------

__global__ __launch_bounds__(256, 4) void gemm_proj(
    const unsigned short* __restrict__ A,   // y [8192][768]
    const unsigned short* __restrict__ Bt,  // wpT [768][768]
    const float* __restrict__ bias,         // [768]
    float* __restrict__ out)                // [8192][768] fp32
{
  __shared__ unsigned short As[2 * 4096];
  __shared__ unsigned short Bs[2 * 4096];
  const int tid = threadIdx.x;
  const int w = tid >> 6, lane = tid & 63;
  const int wm = w >> 1, wn = w & 1;
  const int lr = lane & 15, lq = lane >> 4;
  const int m0 = blockIdx.x * 128, n0 = blockIdx.y * 128;
  const f32x4 fzero = {0.f, 0.f, 0.f, 0.f};

  f32x4 acc[4][4];
  for (int i = 0; i < 4; ++i) for (int j = 0; j < 4; ++j) acc[i][j] = fzero;

  int sbase[2], srow[2], skc[2];
  for (int c = 0; c < 2; ++c) {
    sbase[c] = (c * 4 + w) * 1024;
    int e = (sbase[c] >> 1) + lane * 8;
    srow[c] = e >> 5; skc[c] = e & 31;
  }

  for (int c = 0; c < 2; ++c) {
    ASYNC16(A  + (size_t)(m0 + srow[c]) * 768 + skc[c], (char*)As + sbase[c]);
    ASYNC16(Bt + (size_t)(n0 + srow[c]) * 768 + skc[c], (char*)Bs + sbase[c]);
  }

  for (int kt = 0; kt < 24; ++kt) {
    const int cur = kt & 1;
    asm volatile("s_barrier" ::: "memory");
    if (kt < 23) {
      const int kk0 = (kt + 1) * 32;
      const int dst = (cur ^ 1) * 8192;
      for (int c = 0; c < 2; ++c) {
        ASYNC16(A  + (size_t)(m0 + srow[c]) * 768 + kk0 + skc[c], (char*)As + dst + sbase[c]);
        ASYNC16(Bt + (size_t)(n0 + srow[c]) * 768 + kk0 + skc[c], (char*)Bs + dst + sbase[c]);
      }
      asm volatile("s_waitcnt vmcnt(4)" ::: "memory");
    } else {
      asm volatile("s_waitcnt vmcnt(0)" ::: "memory");
    }
    asm volatile("s_barrier" ::: "memory");

    const unsigned short* Ar = As + cur * 4096;
    const unsigned short* Br = Bs + cur * 4096;
    short8 a[4], b[4];
    for (int i = 0; i < 4; ++i)
      a[i] = *(const short8*)(Ar + (wm * 64 + i * 16 + lr) * 32 + lq * 8);
    for (int j = 0; j < 4; ++j)
      b[j] = *(const short8*)(Br + (wn * 64 + j * 16 + lr) * 32 + lq * 8);
    for (int i = 0; i < 4; ++i)
      for (int j = 0; j < 4; ++j)
        acc[i][j] = __builtin_amdgcn_mfma_f32_16x16x32_bf16(a[i], b[j], acc[i][j], 0, 0, 0);
  }

  for (int j = 0; j < 4; ++j) {
    int col = n0 + wn * 64 + j * 16 + lr;
    float bv = bias[col];
    for (int i = 0; i < 4; ++i) {
      int row0 = m0 + wm * 64 + i * 16 + lq * 4;
      for (int r = 0; r < 4; ++r)
        out[(size_t)(row0 + r) * 768 + col] = acc[i][j][r] + bv;
    }
  }
}

// ---------------- launch ----------------

extern "C" void kernel_launch(void* const* d_in, const int* in_sizes, int n_in,
                              void* d_out, int out_size, void* d_ws, size_t ws_size,
                              hipStream_t stream) {
  const float* x      = (const float*)d_in[0];
  const float* w_attn = (const float*)d_in[1];
  const float* b_attn = (const float*)d_in[2];
  const float* w_proj = (const float*)d_in[3];
  const float* b_proj = (const float*)d_in[4];
  float* out = (float*)d_out;

  char* p = (char*)d_ws;
  unsigned short* xb  = (unsigned short*)p; p += (size_t)8192 * 768 * 2;
  unsigned short* waT = (unsigned short*)p; p += (size_t)2304 * 768 * 2;
  unsigned short* wpT = (unsigned short*)p; p += (size_t)768 * 768 * 2;
  unsigned short* qb  = (unsigned short*)p; p += (size_t)96 * 1024 * 64 * 2;
  unsigned short* kb  = (unsigned short*)p; p += (size_t)96 * 1024 * 64 * 2;
  unsigned short* vTb = (unsigned short*)p; p += (size_t)96 * 64 * 1024 * 2;
  unsigned short* yb  = (unsigned short*)p; p += (size_t)8192 * 768 * 2;

  cvt_bf16<<<6144, 256, 0, stream>>>(x, xb, 8192 * 768);
  transpose_cvt<<<dim3(36, 12), 256, 0, stream>>>(w_attn, waT, 768, 2304);
  transpose_cvt<<<dim3(12, 12), 256, 0, stream>>>(w_proj, wpT, 768, 768);
  gemm_qkv<<<dim3(64, 18), 256, 0, stream>>>(xb, waT, b_attn, qb, kb, vTb);
  attn<<<768, 256, 0, stream>>>(qb, kb, vTb, yb);
  gemm_proj<<<dim3(64, 6), 256, 0, stream>>>(yb, wpT, b_proj, out);
}